// Round 7
// baseline (491.646 us; speedup 1.0000x reference)
//
#include <hip/hip_runtime.h>
#include <hip/hip_bf16.h>
#include <math.h>

#define HIDDEN 1024
#define NH 16
#define HD 64
#define TT 2048
#define NB 4
#define MROWS (TT*NB)          // 8192 rows for projection GEMMs
#define HEADSZ (TT*HD)         // 131072 elements per (b,h) plane

typedef __attribute__((ext_vector_type(8))) __bf16 bf16x8;
typedef __attribute__((ext_vector_type(2))) __bf16 bf16x2;
typedef __attribute__((ext_vector_type(8))) unsigned short u16x8;
typedef __attribute__((ext_vector_type(4))) float f32x4;
typedef __attribute__((ext_vector_type(4))) unsigned int u32x4;

__device__ __forceinline__ unsigned short f2bf(float x) {
  union { float f; unsigned int u; } v; v.f = x;
  unsigned int r = v.u + 0x7fffu + ((v.u >> 16) & 1u);   // RNE
  return (unsigned short)(r >> 16);
}

// two f32 -> packed bf16 pair (lo=a, hi=b); HW op on gfx950 if available
__device__ __forceinline__ unsigned int packpair(float a, float b) {
#if __has_builtin(__builtin_amdgcn_cvt_pk_bf16_f32)
  bf16x2 t = __builtin_amdgcn_cvt_pk_bf16_f32(a, b);
  return __builtin_bit_cast(unsigned int, t);
#else
  return (unsigned int)f2bf(a) | ((unsigned int)f2bf(b) << 16);
#endif
}

__device__ __forceinline__ bf16x8 ld_frag(const unsigned short* p) {
  return __builtin_bit_cast(bf16x8, *(const u16x8*)p);
}

// async global->LDS, 16B per lane. LDS dest = wave-uniform base + lane*16.
__device__ __forceinline__ void gload16(const void* g, void* l) {
  __builtin_amdgcn_global_load_lds(
      (const __attribute__((address_space(1))) void*)g,
      (__attribute__((address_space(3))) void*)l, 16, 0, 0);
}

// stage 32 contiguous elements (16B-aligned dst) from global -> LDS as bf16
__device__ __forceinline__ void stage32(const unsigned short* gp, unsigned short* lp) {
#pragma unroll
  for (int u = 0; u < 4; u++)
    *(u16x8*)(lp + u * 8) = *(const u16x8*)(gp + u * 8);
}
__device__ __forceinline__ void stage32(const float* gp, unsigned short* lp) {
#pragma unroll
  for (int u = 0; u < 4; u++) {
    float4 a0 = *(const float4*)(gp + u * 8);
    float4 a1 = *(const float4*)(gp + u * 8 + 4);
    u32x4 pk;
    pk.x = packpair(a0.x, a0.y); pk.y = packpair(a0.z, a0.w);
    pk.z = packpair(a1.x, a1.y); pk.w = packpair(a1.z, a1.w);
    *(u32x4*)(lp + u * 8) = pk;   // safe: __syncthreads() between write & read
  }
}

// ---------------------------------------------------------------------------
// fp32 -> bf16 bulk converts (memory-bound)
// ---------------------------------------------------------------------------
__global__ __launch_bounds__(256)
void cvt_kernel(const float* __restrict__ s, unsigned short* __restrict__ d, int n4) {
  int i = blockIdx.x * 256 + threadIdx.x;
  if (i >= n4) return;
  float4 f = ((const float4*)s)[i];
  unsigned int lo = packpair(f.x, f.y), hi = packpair(f.z, f.w);
  ((uint2*)d)[i] = make_uint2(lo, hi);
}

// fused 3-way convert: blockIdx.y selects source; dst = d + y*stride4*4
__global__ __launch_bounds__(256)
void cvt3_kernel(const float* __restrict__ a, const float* __restrict__ b,
                 const float* __restrict__ c, unsigned short* __restrict__ d,
                 int n4, long long stride4) {
  const float* s = (blockIdx.y == 0) ? a : (blockIdx.y == 1) ? b : c;
  int i = blockIdx.x * 256 + threadIdx.x;
  if (i >= n4) return;
  float4 f = ((const float4*)s)[i];
  unsigned int lo = packpair(f.x, f.y), hi = packpair(f.z, f.w);
  ((uint2*)d)[(size_t)blockIdx.y * stride4 + i] = make_uint2(lo, hi);
}

// ---------------------------------------------------------------------------
// projc: fused QKV projection (unchanged from R6, 383.4 µs best):
// 2-barrier m97 K-loop, both sides via global_load_lds, 2D grid, and
// epilogue-through-LDS (C tile swizzled into the dead As/Bs, then coalesced
// 16B stores for Q/K and 4B packed sigma-pair stores for V).
// ---------------------------------------------------------------------------
__global__ __launch_bounds__(256)
void projc_kernel(const unsigned short* __restrict__ Xb,   // 3x [MROWS][HIDDEN]
                  const unsigned short* __restrict__ Wb,   // 3x [HIDDEN][HIDDEN]
                  const float* __restrict__ bq, const float* __restrict__ bk,
                  const float* __restrict__ bv,
                  unsigned short* __restrict__ outq, unsigned short* __restrict__ outk,
                  unsigned short* __restrict__ outv)
{
  __shared__ __align__(16) unsigned short SM[2 * 128 * 64];   // As|Bs, aliased as Cs (32 KB)
  unsigned short* As = SM;
  unsigned short* Bs = SM + 128 * 64;

  const int z = blockIdx.z;
  const unsigned short* Xp = Xb + (size_t)z * ((size_t)MROWS * HIDDEN);
  const unsigned short* Wp = Wb + (size_t)z * ((size_t)HIDDEN * HIDDEN);
  const float* bias = (z == 0) ? bq : (z == 1) ? bk : bv;
  unsigned short* out = (z == 0) ? outq : (z == 1) ? outk : outv;

  const int tid = threadIdx.x;
  const int lane = tid & 63;
  const int w = tid >> 6;
  const int wm = w & 1, wn = w >> 1;
  const int lr = lane & 15, lq = lane >> 4;
  const int bm = blockIdx.y, bn = blockIdx.x;

  // staging: wave w, inst u covers rows w*32+u*8 .. +8; lane l -> row +(l>>3),
  // 16B chunk (l&7). LDS dest = uniform base + lane*16 (HW rule) matches.
  const int srow = lane >> 3;            // 0..7
  const int schunk = (lane & 7) * 8;     // short offset in row

  const unsigned short* Ag = Xp + (size_t)(bm * 128 + w * 32 + srow) * HIDDEN + schunk;
  const unsigned short* Bg = Wp + (size_t)(bn * 128 + w * 32 + srow) * HIDDEN + schunk;
  unsigned short* Al = &As[w * 32 * 64];
  unsigned short* Bl = &Bs[w * 32 * 64];

  f32x4 acc[4][4];
#pragma unroll
  for (int i = 0; i < 4; i++)
#pragma unroll
    for (int j = 0; j < 4; j++) acc[i][j] = (f32x4){0.f, 0.f, 0.f, 0.f};

  for (int k0 = 0; k0 < HIDDEN; k0 += 64) {
#pragma unroll
    for (int u = 0; u < 4; u++) {
      gload16(Ag + k0 + u * 8 * HIDDEN, Al + u * 512);
      gload16(Bg + k0 + u * 8 * HIDDEN, Bl + u * 512);
    }
    __syncthreads();   // compiler drains vmcnt(0) before s_barrier
#pragma unroll
    for (int kk = 0; kk < 64; kk += 32) {
      bf16x8 af[4], bfr[4];
#pragma unroll
      for (int i = 0; i < 4; i++)
        af[i] = ld_frag(&As[(wm * 64 + i * 16 + lr) * 64 + kk + lq * 8]);
#pragma unroll
      for (int j = 0; j < 4; j++)
        bfr[j] = ld_frag(&Bs[(wn * 64 + j * 16 + lr) * 64 + kk + lq * 8]);
#pragma unroll
      for (int i = 0; i < 4; i++)
#pragma unroll
        for (int j = 0; j < 4; j++)
          acc[i][j] = __builtin_amdgcn_mfma_f32_16x16x32_bf16(af[i], bfr[j], acc[i][j], 0, 0, 0);
    }
    __syncthreads();   // also: last tile's ds_reads done -> SM reusable as Cs
  }

  // ---- epilogue stage 1: bias+relu6, C tile -> LDS (swizzled bf16) ----
  // C/D layout col=lane&15 (n), row=(lane>>4)*4+reg (m)  [m89-verified]
#pragma unroll
  for (int j = 0; j < 4; j++) {
    const int nl = wn * 64 + j * 16 + lr;
    const float bb = bias[bn * 128 + nl];
#pragma unroll
    for (int i = 0; i < 4; i++) {
#pragma unroll
      for (int r = 0; r < 4; r++) {
        const int ml = wm * 64 + i * 16 + lq * 4 + r;
        float vv = acc[i][j][r] + bb;
        vv = fminf(fmaxf(vv, 0.0f), 6.0f);              // relu6
        SM[(ml * 128 + nl) ^ (((ml >> 2) & 7) << 4)] = f2bf(vv);
      }
    }
  }
  __syncthreads();

  // ---- epilogue stage 2: LDS -> global, coalesced ----
  if (z < 2) {
    // thread = (row m, half): 8x b128 reads, 8x16B contiguous stores
    const int m = tid >> 1, half = tid & 1;
    const int gm = bm * 128 + m;
    const int t = gm >> 2, b = gm & 3;
    const int h = bn * 2 + half;
    unsigned short* op = out + (size_t)(b * NH + h) * HEADSZ + (size_t)t * HD;
    const int xr = ((m >> 2) & 7) << 4;
#pragma unroll
    for (int c8 = 0; c8 < 8; c8++) {
      const int idx = (m * 128 + half * 64 + c8 * 8) ^ xr;
      *(u16x8*)(op + c8 * 8) = *(const u16x8*)&SM[idx];
    }
  } else {
    // V: out[b][h][d][stq*128 + a], a = (sl&15)*8 + (sl>>4), sl = (bm&3)*32+s_local.
    const int g = tid >> 4, e = tid & 15;
    const int stq = bm >> 2;
    const int f0 = (bm & 3) * 2;
    const int m1 = e * 4, m2 = m1 + 64;
    const int x1 = ((m1 >> 2) & 7) << 4;
    const int x2 = (((m2 >> 2)) & 7) << 4;
#pragma unroll
    for (int it = 0; it < 32; it++) {
      const int idx2 = g * 32 + it;           // (n_local, b)
      const int nl = idx2 >> 2, b = idx2 & 3;
      const int n = bn * 128 + nl;
      const int h = n >> 6, d = n & 63;
      const unsigned short v1 = SM[((m1 + b) * 128 + nl) ^ x1];
      const unsigned short v2 = SM[((m2 + b) * 128 + nl) ^ x2];
      const unsigned int pk = (unsigned int)v1 | ((unsigned int)v2 << 16);
      unsigned short* op = out + (size_t)(b * NH + h) * HEADSZ + (size_t)d * TT
                               + stq * 128 + e * 8 + f0;
      *(unsigned int*)op = pk;
    }
  }
}

// ---------------------------------------------------------------------------
// Single-z projection (round-1 projg) -- PATH B fallback (ws fits 1 X buffer)
// ---------------------------------------------------------------------------
template<int VT>
__global__ __launch_bounds__(256)
void projg_kernel(const unsigned short* __restrict__ Xp, const unsigned short* __restrict__ Wp,
                  const float* __restrict__ bias, unsigned short* __restrict__ out)
{
  __shared__ __align__(16) unsigned short As[128 * 64];
  __shared__ __align__(16) unsigned short Bs[128 * 64];

  const int tid = threadIdx.x;
  const int lane = tid & 63;
  const int w = tid >> 6;
  const int wm = w & 1, wn = w >> 1;
  const int lr = lane & 15, lq = lane >> 4;
  const int bm = blockIdx.y, bn = blockIdx.x;

  const int srow = lane >> 3;
  const int schunk = (lane & 7) * 8;

  const unsigned short* Ag = Xp + (size_t)(bm * 128 + w * 32 + srow) * HIDDEN + schunk;
  const unsigned short* Bg = Wp + (size_t)(bn * 128 + w * 32 + srow) * HIDDEN + schunk;
  unsigned short* Al = &As[w * 32 * 64];
  unsigned short* Bl = &Bs[w * 32 * 64];

  f32x4 acc[4][4];
#pragma unroll
  for (int i = 0; i < 4; i++)
#pragma unroll
    for (int j = 0; j < 4; j++) acc[i][j] = (f32x4){0.f, 0.f, 0.f, 0.f};

  for (int k0 = 0; k0 < HIDDEN; k0 += 64) {
#pragma unroll
    for (int u = 0; u < 4; u++) {
      gload16(Ag + k0 + u * 8 * HIDDEN, Al + u * 512);
      gload16(Bg + k0 + u * 8 * HIDDEN, Bl + u * 512);
    }
    __syncthreads();
#pragma unroll
    for (int kk = 0; kk < 64; kk += 32) {
      bf16x8 af[4], bfr[4];
#pragma unroll
      for (int i = 0; i < 4; i++)
        af[i] = ld_frag(&As[(wm * 64 + i * 16 + lr) * 64 + kk + lq * 8]);
#pragma unroll
      for (int j = 0; j < 4; j++)
        bfr[j] = ld_frag(&Bs[(wn * 64 + j * 16 + lr) * 64 + kk + lq * 8]);
#pragma unroll
      for (int i = 0; i < 4; i++)
#pragma unroll
        for (int j = 0; j < 4; j++)
          acc[i][j] = __builtin_amdgcn_mfma_f32_16x16x32_bf16(af[i], bfr[j], acc[i][j], 0, 0, 0);
    }
    __syncthreads();
  }

#pragma unroll
  for (int j = 0; j < 4; j++) {
    const int n = bn * 128 + wn * 64 + j * 16 + lr;
    const float bb = bias[n];
    const int h = n >> 6, d = n & 63;
#pragma unroll
    for (int i = 0; i < 4; i++) {
      const int mb = bm * 128 + wm * 64 + i * 16 + lq * 4;
#pragma unroll
      for (int r = 0; r < 4; r++) {
        const int m = mb + r;
        const int t = m >> 2, b = m & 3;
        float vv = acc[i][j][r] + bb;
        vv = fminf(fmaxf(vv, 0.0f), 6.0f);
        if (VT) {
          const int s = t;
          const int st = s >> 7, sl = s & 127;
          const int a = (sl & 15) * 8 + (sl >> 4);
          out[(size_t)(b * NH + h) * HEADSZ + (size_t)d * TT + st * 128 + a] = f2bf(vv);
        } else {
          out[(size_t)(b * NH + h) * HEADSZ + (size_t)t * HD + d] = f2bf(vv);
        }
      }
    }
  }
}

// ---------------------------------------------------------------------------
// Projection fallback (fp32/mixed reg-staged; used when workspace is tight)
// ---------------------------------------------------------------------------
#define PLD 72

template<int VT, typename XT, typename WT>
__global__ __launch_bounds__(256, 3)
void proj_kernel(const XT* __restrict__ Xp, const WT* __restrict__ Wp,
                 const float* __restrict__ bias, unsigned short* __restrict__ out)
{
  __shared__ unsigned short As[128 * PLD];
  __shared__ unsigned short Bs[128 * PLD];

  const int tid = threadIdx.x;
  const int lane = tid & 63;
  const int wid = tid >> 6;
  const int wm = wid & 1, wn = wid >> 1;
  const int lr = lane & 15, lq = lane >> 4;
  const int bm = blockIdx.y, bn = blockIdx.x;

  const int srow = tid >> 1;            // 0..127
  const int scol = (tid & 1) * 32;      // 0 or 32

  const XT* Ap = Xp + (size_t)(bm * 128 + srow) * HIDDEN + scol;
  const WT* Bp = Wp + (size_t)(bn * 128 + srow) * HIDDEN + scol;
  unsigned short* Asw = &As[srow * PLD + scol];
  unsigned short* Bsw = &Bs[srow * PLD + scol];

  f32x4 acc[4][4];
#pragma unroll
  for (int i = 0; i < 4; i++)
#pragma unroll
    for (int j = 0; j < 4; j++) acc[i][j] = (f32x4){0.f, 0.f, 0.f, 0.f};

  for (int k0 = 0; k0 < HIDDEN; k0 += 64) {
    stage32(Ap + k0, Asw);
    stage32(Bp + k0, Bsw);
    __syncthreads();
#pragma unroll
    for (int kk = 0; kk < 64; kk += 32) {
      bf16x8 af[4], bfr[4];
#pragma unroll
      for (int i = 0; i < 4; i++)
        af[i] = ld_frag(&As[(wm * 64 + i * 16 + lr) * PLD + kk + lq * 8]);
#pragma unroll
      for (int j = 0; j < 4; j++)
        bfr[j] = ld_frag(&Bs[(wn * 64 + j * 16 + lr) * PLD + kk + lq * 8]);
#pragma unroll
      for (int i = 0; i < 4; i++)
#pragma unroll
        for (int j = 0; j < 4; j++)
          acc[i][j] = __builtin_amdgcn_mfma_f32_16x16x32_bf16(af[i], bfr[j], acc[i][j], 0, 0, 0);
    }
    __syncthreads();
  }

#pragma unroll
  for (int j = 0; j < 4; j++) {
    const int n = bn * 128 + wn * 64 + j * 16 + lr;
    const float bb = bias[n];
    const int h = n >> 6, d = n & 63;
#pragma unroll
    for (int i = 0; i < 4; i++) {
      const int mb = bm * 128 + wm * 64 + i * 16 + lq * 4;
#pragma unroll
      for (int r = 0; r < 4; r++) {
        const int m = mb + r;
        const int t = m >> 2, b = m & 3;
        float vv = acc[i][j][r] + bb;
        vv = fminf(fmaxf(vv, 0.0f), 6.0f);              // relu6
        if (VT) {
          const int s = t;
          const int st = s >> 7, sl = s & 127;
          const int a = (sl & 15) * 8 + (sl >> 4);
          out[(size_t)(b * NH + h) * HEADSZ + (size_t)d * TT + st * 128 + a] = f2bf(vv);
        } else {
          out[(size_t)(b * NH + h) * HEADSZ + (size_t)t * HD + d] = f2bf(vv);
        }
      }
    }
  }
}

// ---------------------------------------------------------------------------
// Flash attention, fixed-bias softmax (no online max):
//   P = exp2(S*csc - MBIAS), O = (P@V), l = (P@ones); out = O/l.
// R7 change (guide lesson #7 / m169): V is NOT LDS-staged. Each (b,h)
// V-plane is 256 KB -> L2-resident, and vh is already in PV-fragment order;
// PV reads V directly from global (per-ks hoist of 4x b128 = 16 transient
// VGPRs, not the spill-prone whole-tile hoist). Drops 17.4 KB LDS + Vt
// staging stores -> LDS 34816 B -> 4 blocks/CU (was 3).
// KPs union buffer: K tile @ stride 72 during QK^T, P tile @ stride 136
// after (barrier between: P clobbers K rows other waves read).
// ---------------------------------------------------------------------------
#define QLD 72
#define PLDS 136
#define MBIAS 24.0f

__global__ __launch_bounds__(256, 4)
void attn_kernel(const unsigned short* __restrict__ qh,
                 const unsigned short* __restrict__ kh,
                 const unsigned short* __restrict__ vh,
                 float* __restrict__ outp)
{
  __shared__ unsigned short KPs[128 * PLDS];   // 34816 B (K @72 / P @136)

  const int tid = threadIdx.x;
  const int lane = tid & 63;
  const int w = tid >> 6;
  const int lr = lane & 15, lq = lane >> 4;
  const int qt = blockIdx.x, bh = blockIdx.y;
  const int b = bh >> 4, h = bh & 15;
  const int t0 = qt * 128;

  const size_t headoff = (size_t)bh * HEADSZ;

  // ---- load Q tile through LDS once, keep fragments in registers ----
  {
    const unsigned short* qb = qh + headoff + (size_t)t0 * HD;
    const int row = tid >> 1, c0 = (tid & 1) * 32;
    stage32(qb + (size_t)row * HD + c0, &KPs[row * QLD + c0]);
  }
  __syncthreads();
  bf16x8 aq[2][2];
#pragma unroll
  for (int i = 0; i < 2; i++)
#pragma unroll
    for (int kx = 0; kx < 2; kx++)
      aq[i][kx] = ld_frag(&KPs[(w * 32 + i * 16 + lr) * QLD + kx * 32 + lq * 8]);
  __syncthreads();

  // ones-column B-frag (B[n]=1 iff n==0) -- l accumulates as O column 0
  union { u16x8 v; unsigned short s[8]; } uo;
  const unsigned short ov = (lr == 0) ? (unsigned short)0x3F80 : (unsigned short)0;
#pragma unroll
  for (int z = 0; z < 8; z++) uo.s[z] = ov;
  const bf16x8 onesf = __builtin_bit_cast(bf16x8, uo.v);

  f32x4 Oacc[2][4];
  f32x4 lacc[2];
#pragma unroll
  for (int i = 0; i < 2; i++) {
#pragma unroll
    for (int jo = 0; jo < 4; jo++) Oacc[i][jo] = (f32x4){0.f, 0.f, 0.f, 0.f};
    lacc[i] = (f32x4){0.f, 0.f, 0.f, 0.f};
  }

  const float csc = 0.1803368801111204f;   // log2(e) / sqrt(64)

  // per-lane V base: PV fragment (jo,ks) reads vh[d = jo*16+lr][a = st*128 + ks + lq*8]
  const unsigned short* vrow = vh + headoff + (size_t)lr * TT + lq * 8;

  for (int st = 0; st < TT / 128; st++) {
    // ---- stage K tile [s][d] @ stride QLD ----
    {
      const unsigned short* kb = kh + headoff + (size_t)st * (128 * HD);
      const int row = tid >> 1, c0 = (tid & 1) * 32;
      stage32(kb + (size_t)row * HD + c0, &KPs[row * QLD + c0]);
    }
    __syncthreads();

    // ---- S = Q K^T ----
    f32x4 sc[2][8];
#pragma unroll
    for (int i = 0; i < 2; i++)
#pragma unroll
      for (int j = 0; j < 8; j++) sc[i][j] = (f32x4){0.f, 0.f, 0.f, 0.f};

    __builtin_amdgcn_s_setprio(1);
#pragma unroll
    for (int kx = 0; kx < 2; kx++) {
#pragma unroll
      for (int j = 0; j < 8; j++) {
        bf16x8 bk = ld_frag(&KPs[(j * 16 + lr) * QLD + kx * 32 + lq * 8]);
#pragma unroll
        for (int i = 0; i < 2; i++)
          sc[i][j] = __builtin_amdgcn_mfma_f32_16x16x32_bf16(aq[i][kx], bk, sc[i][j], 0, 0, 0);
      }
    }
    __builtin_amdgcn_s_setprio(0);
    __syncthreads();   // all K reads done before P overwrites the union buffer

    // ---- P = exp2(S*csc - MBIAS)  (no max pass, no rescale) ----
#pragma unroll
    for (int i = 0; i < 2; i++)
#pragma unroll
      for (int j = 0; j < 8; j++)
#pragma unroll
        for (int r = 0; r < 4; r++)
          sc[i][j][r] = exp2f(fmaf(sc[i][j][r], csc, -MBIAS));

    // ---- P -> LDS @ stride PLDS: lane's 8 cols contiguous at kpos=lr*8 ----
    // Psm[m][k=lr*8+j] = P[m][s_local = j*16+lr]  (matches vh's sigma order)
#pragma unroll
    for (int i = 0; i < 2; i++)
#pragma unroll
      for (int r = 0; r < 4; r++) {
        const int row = w * 32 + i * 16 + lq * 4 + r;
        u32x4 pk;
        pk.x = packpair(sc[i][0][r], sc[i][1][r]);
        pk.y = packpair(sc[i][2][r], sc[i][3][r]);
        pk.z = packpair(sc[i][4][r], sc[i][5][r]);
        pk.w = packpair(sc[i][6][r], sc[i][7][r]);
        *(u16x8*)&KPs[row * PLDS + lr * 8] = __builtin_bit_cast(u16x8, pk);
      }
    __syncthreads();   // P visible before PV reads

    // ---- O += P V  (+ l via ones column); V direct from global (L2-hit) ----
    const unsigned short* vt = vrow + st * 128;
    __builtin_amdgcn_s_setprio(1);
#pragma unroll
    for (int ks = 0; ks < 128; ks += 32) {
      bf16x8 ap[2];
#pragma unroll
      for (int i = 0; i < 2; i++)
        ap[i] = ld_frag(&KPs[(w * 32 + i * 16 + lr) * PLDS + ks + lq * 8]);
      bf16x8 bvr[4];
#pragma unroll
      for (int jo = 0; jo < 4; jo++)
        bvr[jo] = ld_frag(vt + (size_t)(jo * 16) * TT + ks);
#pragma unroll
      for (int jo = 0; jo < 4; jo++)
#pragma unroll
        for (int i = 0; i < 2; i++)
          Oacc[i][jo] = __builtin_amdgcn_mfma_f32_16x16x32_bf16(ap[i], bvr[jo], Oacc[i][jo], 0, 0, 0);
#pragma unroll
      for (int i = 0; i < 2; i++)
        lacc[i] = __builtin_amdgcn_mfma_f32_16x16x32_bf16(ap[i], onesf, lacc[i], 0, 0, 0);
    }
    __builtin_amdgcn_s_setprio(0);
    __syncthreads();   // P reads done before next iteration's K staging
  }

  // ---- epilogue: l sits in col 0 (lanes lr==0); broadcast within 16-group ----
#pragma unroll
  for (int i = 0; i < 2; i++)
#pragma unroll
    for (int r = 0; r < 4; r++) {
      const float l = __shfl(lacc[i][r], lane & 48);
      const float inv = 1.0f / l;
      const int t = t0 + w * 32 + i * 16 + lq * 4 + r;
      float* op = outp + ((size_t)t * NB + b) * HIDDEN + h * HD;
#pragma unroll
      for (int jo = 0; jo < 4; jo++)
        op[jo * 16 + lr] = Oacc[i][jo][r] * inv;
    }
}

extern "C" void kernel_launch(void* const* d_in, const int* in_sizes, int n_in,
                              void* d_out, int out_size, void* d_ws, size_t ws_size,
                              hipStream_t stream)
{
  const float* q  = (const float*)d_in[0];
  const float* k  = (const float*)d_in[1];
  const float* v  = (const float*)d_in[2];
  const float* Wq = (const float*)d_in[3];
  const float* bq = (const float*)d_in[4];
  const float* Wk = (const float*)d_in[5];
  const float* bk = (const float*)d_in[6];
  const float* Wv = (const float*)d_in[7];
  const float* bv = (const float*)d_in[8];

  const size_t actN = (size_t)MROWS * HIDDEN;       // 8.4M elements
  const size_t WN   = (size_t)HIDDEN * HIDDEN;      // 1M elements
  unsigned short* qh  = (unsigned short*)d_ws;
  unsigned short* kh  = qh + actN;
  unsigned short* vh  = kh + actN;                  // vh: [b][h][d][perm-s]
  unsigned short* Wb3 = vh + actN;                  // 3x converted W (6.3 MB)
  unsigned short* Xb3 = Wb3 + 3 * WN;               // 3x converted X (50.3 MB)

  const size_t need_fused = (6 * actN + 3 * WN) * 2;     // 107.0 MB
  const size_t need_full  = (4 * actN + WN) * 2;         // 69.2 MB
  const size_t need_w     = (3 * actN + WN) * 2;         // 52.4 MB

  const int n4a = (int)(actN / 4);
  const int n4w = (int)(WN / 4);
  dim3 cga((n4a + 255) / 256), cgw((n4w + 255) / 256);
  dim3 pg(HIDDEN / 128, MROWS / 128);               // (8, 64)
  dim3 pf(HIDDEN / 128, MROWS / 128, 3);            // (8, 64, 3) fused
  dim3 ag(TT / 128, NB * NH);                       // (16, 64)

  if (ws_size >= need_fused) {
    dim3 cw(cgw.x, 3), cx(cga.x, 3);
    cvt3_kernel<<<cw, 256, 0, stream>>>(Wq, Wk, Wv, Wb3, n4w, (long long)(WN / 4));
    cvt3_kernel<<<cx, 256, 0, stream>>>(q, k, v, Xb3, n4a, (long long)(actN / 4));
    projc_kernel<<<pf, 256, 0, stream>>>(Xb3, Wb3, bq, bk, bv, qh, kh, vh);
  } else if (ws_size >= need_full) {
    unsigned short* Wbf = vh + actN;
    unsigned short* Xbf = Wbf + WN;
    cvt_kernel<<<cga, 256, 0, stream>>>(q, Xbf, n4a);
    cvt_kernel<<<cgw, 256, 0, stream>>>(Wq, Wbf, n4w);
    projg_kernel<0><<<pg, 256, 0, stream>>>(Xbf, Wbf, bq, qh);
    cvt_kernel<<<cga, 256, 0, stream>>>(k, Xbf, n4a);
    cvt_kernel<<<cgw, 256, 0, stream>>>(Wk, Wbf, n4w);
    projg_kernel<0><<<pg, 256, 0, stream>>>(Xbf, Wbf, bk, kh);
    cvt_kernel<<<cga, 256, 0, stream>>>(v, Xbf, n4a);
    cvt_kernel<<<cgw, 256, 0, stream>>>(Wv, Wbf, n4w);
    projg_kernel<1><<<pg, 256, 0, stream>>>(Xbf, Wbf, bv, vh);
  } else if (ws_size >= need_w) {
    unsigned short* Wbf = vh + actN;
    cvt_kernel<<<cgw, 256, 0, stream>>>(Wq, Wbf, n4w);
    proj_kernel<0, float, unsigned short><<<pg, 256, 0, stream>>>(q, Wbf, bq, qh);
    cvt_kernel<<<cgw, 256, 0, stream>>>(Wk, Wbf, n4w);
    proj_kernel<0, float, unsigned short><<<pg, 256, 0, stream>>>(k, Wbf, bk, kh);
    cvt_kernel<<<cgw, 256, 0, stream>>>(Wv, Wbf, n4w);
    proj_kernel<1, float, unsigned short><<<pg, 256, 0, stream>>>(v, Wbf, bv, vh);
  } else {
    proj_kernel<0, float, float><<<pg, 256, 0, stream>>>(q, Wq, bq, qh);
    proj_kernel<0, float, float><<<pg, 256, 0, stream>>>(k, Wk, bk, kh);
    proj_kernel<1, float, float><<<pg, 256, 0, stream>>>(v, Wv, bv, vh);
  }

  attn_kernel<<<ag, 256, 0, stream>>>(qh, kh, vh, (float*)d_out);
}

// Round 9
// 375.523 us; speedup vs baseline: 1.3092x; 1.3092x over previous
//
#include <hip/hip_runtime.h>
#include <hip/hip_bf16.h>
#include <math.h>

#define HIDDEN 1024
#define NH 16
#define HD 64
#define TT 2048
#define NB 4
#define MROWS (TT*NB)          // 8192 rows for projection GEMMs
#define HEADSZ (TT*HD)         // 131072 elements per (b,h) plane

typedef __attribute__((ext_vector_type(8))) __bf16 bf16x8;
typedef __attribute__((ext_vector_type(2))) __bf16 bf16x2;
typedef __attribute__((ext_vector_type(8))) unsigned short u16x8;
typedef __attribute__((ext_vector_type(4))) float f32x4;
typedef __attribute__((ext_vector_type(4))) unsigned int u32x4;

__device__ __forceinline__ unsigned short f2bf(float x) {
  union { float f; unsigned int u; } v; v.f = x;
  unsigned int r = v.u + 0x7fffu + ((v.u >> 16) & 1u);   // RNE
  return (unsigned short)(r >> 16);
}

// two f32 -> packed bf16 pair (lo=a, hi=b); HW op on gfx950 if available
__device__ __forceinline__ unsigned int packpair(float a, float b) {
#if __has_builtin(__builtin_amdgcn_cvt_pk_bf16_f32)
  bf16x2 t = __builtin_amdgcn_cvt_pk_bf16_f32(a, b);
  return __builtin_bit_cast(unsigned int, t);
#else
  return (unsigned int)f2bf(a) | ((unsigned int)f2bf(b) << 16);
#endif
}

__device__ __forceinline__ bf16x8 ld_frag(const unsigned short* p) {
  return __builtin_bit_cast(bf16x8, *(const u16x8*)p);
}

// async global->LDS, 16B per lane. LDS dest = wave-uniform base + lane*16.
__device__ __forceinline__ void gload16(const void* g, void* l) {
  __builtin_amdgcn_global_load_lds(
      (const __attribute__((address_space(1))) void*)g,
      (__attribute__((address_space(3))) void*)l, 16, 0, 0);
}

// stage 32 contiguous elements (16B-aligned dst) from global -> LDS as bf16
__device__ __forceinline__ void stage32(const unsigned short* gp, unsigned short* lp) {
#pragma unroll
  for (int u = 0; u < 4; u++)
    *(u16x8*)(lp + u * 8) = *(const u16x8*)(gp + u * 8);
}
__device__ __forceinline__ void stage32(const float* gp, unsigned short* lp) {
#pragma unroll
  for (int u = 0; u < 4; u++) {
    float4 a0 = *(const float4*)(gp + u * 8);
    float4 a1 = *(const float4*)(gp + u * 8 + 4);
    u32x4 pk;
    pk.x = packpair(a0.x, a0.y); pk.y = packpair(a0.z, a0.w);
    pk.z = packpair(a1.x, a1.y); pk.w = packpair(a1.z, a1.w);
    *(u32x4*)(lp + u * 8) = pk;   // safe: __syncthreads() between write & read
  }
}

// ---------------------------------------------------------------------------
// fp32 -> bf16 bulk converts (memory-bound)
// ---------------------------------------------------------------------------
__global__ __launch_bounds__(256)
void cvt_kernel(const float* __restrict__ s, unsigned short* __restrict__ d, int n4) {
  int i = blockIdx.x * 256 + threadIdx.x;
  if (i >= n4) return;
  float4 f = ((const float4*)s)[i];
  unsigned int lo = packpair(f.x, f.y), hi = packpair(f.z, f.w);
  ((uint2*)d)[i] = make_uint2(lo, hi);
}

// fused 3-way convert: blockIdx.y selects source; dst = d + y*stride4*4
__global__ __launch_bounds__(256)
void cvt3_kernel(const float* __restrict__ a, const float* __restrict__ b,
                 const float* __restrict__ c, unsigned short* __restrict__ d,
                 int n4, long long stride4) {
  const float* s = (blockIdx.y == 0) ? a : (blockIdx.y == 1) ? b : c;
  int i = blockIdx.x * 256 + threadIdx.x;
  if (i >= n4) return;
  float4 f = ((const float4*)s)[i];
  unsigned int lo = packpair(f.x, f.y), hi = packpair(f.z, f.w);
  ((uint2*)d)[(size_t)blockIdx.y * stride4 + i] = make_uint2(lo, hi);
}

// ---------------------------------------------------------------------------
// projc: fused QKV projection (unchanged from R6, best config):
// 2-barrier m97 K-loop, both sides via global_load_lds, 2D grid, and
// epilogue-through-LDS (C tile swizzled into the dead As/Bs, then coalesced
// 16B stores for Q/K and 4B packed sigma-pair stores for V).
// ---------------------------------------------------------------------------
__global__ __launch_bounds__(256)
void projc_kernel(const unsigned short* __restrict__ Xb,   // 3x [MROWS][HIDDEN]
                  const unsigned short* __restrict__ Wb,   // 3x [HIDDEN][HIDDEN]
                  const float* __restrict__ bq, const float* __restrict__ bk,
                  const float* __restrict__ bv,
                  unsigned short* __restrict__ outq, unsigned short* __restrict__ outk,
                  unsigned short* __restrict__ outv)
{
  __shared__ __align__(16) unsigned short SM[2 * 128 * 64];   // As|Bs, aliased as Cs (32 KB)
  unsigned short* As = SM;
  unsigned short* Bs = SM + 128 * 64;

  const int z = blockIdx.z;
  const unsigned short* Xp = Xb + (size_t)z * ((size_t)MROWS * HIDDEN);
  const unsigned short* Wp = Wb + (size_t)z * ((size_t)HIDDEN * HIDDEN);
  const float* bias = (z == 0) ? bq : (z == 1) ? bk : bv;
  unsigned short* out = (z == 0) ? outq : (z == 1) ? outk : outv;

  const int tid = threadIdx.x;
  const int lane = tid & 63;
  const int w = tid >> 6;
  const int wm = w & 1, wn = w >> 1;
  const int lr = lane & 15, lq = lane >> 4;
  const int bm = blockIdx.y, bn = blockIdx.x;

  // staging: wave w, inst u covers rows w*32+u*8 .. +8; lane l -> row +(l>>3),
  // 16B chunk (l&7). LDS dest = uniform base + lane*16 (HW rule) matches.
  const int srow = lane >> 3;            // 0..7
  const int schunk = (lane & 7) * 8;     // short offset in row

  const unsigned short* Ag = Xp + (size_t)(bm * 128 + w * 32 + srow) * HIDDEN + schunk;
  const unsigned short* Bg = Wp + (size_t)(bn * 128 + w * 32 + srow) * HIDDEN + schunk;
  unsigned short* Al = &As[w * 32 * 64];
  unsigned short* Bl = &Bs[w * 32 * 64];

  f32x4 acc[4][4];
#pragma unroll
  for (int i = 0; i < 4; i++)
#pragma unroll
    for (int j = 0; j < 4; j++) acc[i][j] = (f32x4){0.f, 0.f, 0.f, 0.f};

  for (int k0 = 0; k0 < HIDDEN; k0 += 64) {
#pragma unroll
    for (int u = 0; u < 4; u++) {
      gload16(Ag + k0 + u * 8 * HIDDEN, Al + u * 512);
      gload16(Bg + k0 + u * 8 * HIDDEN, Bl + u * 512);
    }
    __syncthreads();   // compiler drains vmcnt(0) before s_barrier
#pragma unroll
    for (int kk = 0; kk < 64; kk += 32) {
      bf16x8 af[4], bfr[4];
#pragma unroll
      for (int i = 0; i < 4; i++)
        af[i] = ld_frag(&As[(wm * 64 + i * 16 + lr) * 64 + kk + lq * 8]);
#pragma unroll
      for (int j = 0; j < 4; j++)
        bfr[j] = ld_frag(&Bs[(wn * 64 + j * 16 + lr) * 64 + kk + lq * 8]);
#pragma unroll
      for (int i = 0; i < 4; i++)
#pragma unroll
        for (int j = 0; j < 4; j++)
          acc[i][j] = __builtin_amdgcn_mfma_f32_16x16x32_bf16(af[i], bfr[j], acc[i][j], 0, 0, 0);
    }
    __syncthreads();   // also: last tile's ds_reads done -> SM reusable as Cs
  }

  // ---- epilogue stage 1: bias+relu6, C tile -> LDS (swizzled bf16) ----
  // C/D layout col=lane&15 (n), row=(lane>>4)*4+reg (m)  [m89-verified]
#pragma unroll
  for (int j = 0; j < 4; j++) {
    const int nl = wn * 64 + j * 16 + lr;
    const float bb = bias[bn * 128 + nl];
#pragma unroll
    for (int i = 0; i < 4; i++) {
#pragma unroll
      for (int r = 0; r < 4; r++) {
        const int ml = wm * 64 + i * 16 + lq * 4 + r;
        float vv = acc[i][j][r] + bb;
        vv = fminf(fmaxf(vv, 0.0f), 6.0f);              // relu6
        SM[(ml * 128 + nl) ^ (((ml >> 2) & 7) << 4)] = f2bf(vv);
      }
    }
  }
  __syncthreads();

  // ---- epilogue stage 2: LDS -> global, coalesced ----
  if (z < 2) {
    // thread = (row m, half): 8x b128 reads, 8x16B contiguous stores
    const int m = tid >> 1, half = tid & 1;
    const int gm = bm * 128 + m;
    const int t = gm >> 2, b = gm & 3;
    const int h = bn * 2 + half;
    unsigned short* op = out + (size_t)(b * NH + h) * HEADSZ + (size_t)t * HD;
    const int xr = ((m >> 2) & 7) << 4;
#pragma unroll
    for (int c8 = 0; c8 < 8; c8++) {
      const int idx = (m * 128 + half * 64 + c8 * 8) ^ xr;
      *(u16x8*)(op + c8 * 8) = *(const u16x8*)&SM[idx];
    }
  } else {
    // V: out[b][h][d][stq*128 + a], a = (sl&15)*8 + (sl>>4), sl = (bm&3)*32+s_local.
    const int g = tid >> 4, e = tid & 15;
    const int stq = bm >> 2;
    const int f0 = (bm & 3) * 2;
    const int m1 = e * 4, m2 = m1 + 64;
    const int x1 = ((m1 >> 2) & 7) << 4;
    const int x2 = (((m2 >> 2)) & 7) << 4;
#pragma unroll
    for (int it = 0; it < 32; it++) {
      const int idx2 = g * 32 + it;           // (n_local, b)
      const int nl = idx2 >> 2, b = idx2 & 3;
      const int n = bn * 128 + nl;
      const int h = n >> 6, d = n & 63;
      const unsigned short v1 = SM[((m1 + b) * 128 + nl) ^ x1];
      const unsigned short v2 = SM[((m2 + b) * 128 + nl) ^ x2];
      const unsigned int pk = (unsigned int)v1 | ((unsigned int)v2 << 16);
      unsigned short* op = out + (size_t)(b * NH + h) * HEADSZ + (size_t)d * TT
                               + stq * 128 + e * 8 + f0;
      *(unsigned int*)op = pk;
    }
  }
}

// ---------------------------------------------------------------------------
// Single-z projection (round-1 projg) -- PATH B fallback (ws fits 1 X buffer)
// ---------------------------------------------------------------------------
template<int VT>
__global__ __launch_bounds__(256)
void projg_kernel(const unsigned short* __restrict__ Xp, const unsigned short* __restrict__ Wp,
                  const float* __restrict__ bias, unsigned short* __restrict__ out)
{
  __shared__ __align__(16) unsigned short As[128 * 64];
  __shared__ __align__(16) unsigned short Bs[128 * 64];

  const int tid = threadIdx.x;
  const int lane = tid & 63;
  const int w = tid >> 6;
  const int wm = w & 1, wn = w >> 1;
  const int lr = lane & 15, lq = lane >> 4;
  const int bm = blockIdx.y, bn = blockIdx.x;

  const int srow = lane >> 3;
  const int schunk = (lane & 7) * 8;

  const unsigned short* Ag = Xp + (size_t)(bm * 128 + w * 32 + srow) * HIDDEN + schunk;
  const unsigned short* Bg = Wp + (size_t)(bn * 128 + w * 32 + srow) * HIDDEN + schunk;
  unsigned short* Al = &As[w * 32 * 64];
  unsigned short* Bl = &Bs[w * 32 * 64];

  f32x4 acc[4][4];
#pragma unroll
  for (int i = 0; i < 4; i++)
#pragma unroll
    for (int j = 0; j < 4; j++) acc[i][j] = (f32x4){0.f, 0.f, 0.f, 0.f};

  for (int k0 = 0; k0 < HIDDEN; k0 += 64) {
#pragma unroll
    for (int u = 0; u < 4; u++) {
      gload16(Ag + k0 + u * 8 * HIDDEN, Al + u * 512);
      gload16(Bg + k0 + u * 8 * HIDDEN, Bl + u * 512);
    }
    __syncthreads();
#pragma unroll
    for (int kk = 0; kk < 64; kk += 32) {
      bf16x8 af[4], bfr[4];
#pragma unroll
      for (int i = 0; i < 4; i++)
        af[i] = ld_frag(&As[(wm * 64 + i * 16 + lr) * 64 + kk + lq * 8]);
#pragma unroll
      for (int j = 0; j < 4; j++)
        bfr[j] = ld_frag(&Bs[(wn * 64 + j * 16 + lr) * 64 + kk + lq * 8]);
#pragma unroll
      for (int i = 0; i < 4; i++)
#pragma unroll
        for (int j = 0; j < 4; j++)
          acc[i][j] = __builtin_amdgcn_mfma_f32_16x16x32_bf16(af[i], bfr[j], acc[i][j], 0, 0, 0);
    }
    __syncthreads();
  }

#pragma unroll
  for (int j = 0; j < 4; j++) {
    const int n = bn * 128 + wn * 64 + j * 16 + lr;
    const float bb = bias[n];
    const int h = n >> 6, d = n & 63;
#pragma unroll
    for (int i = 0; i < 4; i++) {
      const int mb = bm * 128 + wm * 64 + i * 16 + lq * 4;
#pragma unroll
      for (int r = 0; r < 4; r++) {
        const int m = mb + r;
        const int t = m >> 2, b = m & 3;
        float vv = acc[i][j][r] + bb;
        vv = fminf(fmaxf(vv, 0.0f), 6.0f);
        if (VT) {
          const int s = t;
          const int st = s >> 7, sl = s & 127;
          const int a = (sl & 15) * 8 + (sl >> 4);
          out[(size_t)(b * NH + h) * HEADSZ + (size_t)d * TT + st * 128 + a] = f2bf(vv);
        } else {
          out[(size_t)(b * NH + h) * HEADSZ + (size_t)t * HD + d] = f2bf(vv);
        }
      }
    }
  }
}

// ---------------------------------------------------------------------------
// Projection fallback (fp32/mixed reg-staged; used when workspace is tight)
// ---------------------------------------------------------------------------
#define PLD 72

template<int VT, typename XT, typename WT>
__global__ __launch_bounds__(256, 3)
void proj_kernel(const XT* __restrict__ Xp, const WT* __restrict__ Wp,
                 const float* __restrict__ bias, unsigned short* __restrict__ out)
{
  __shared__ unsigned short As[128 * PLD];
  __shared__ unsigned short Bs[128 * PLD];

  const int tid = threadIdx.x;
  const int lane = tid & 63;
  const int wid = tid >> 6;
  const int wm = wid & 1, wn = wid >> 1;
  const int lr = lane & 15, lq = lane >> 4;
  const int bm = blockIdx.y, bn = blockIdx.x;

  const int srow = tid >> 1;            // 0..127
  const int scol = (tid & 1) * 32;      // 0 or 32

  const XT* Ap = Xp + (size_t)(bm * 128 + srow) * HIDDEN + scol;
  const WT* Bp = Wp + (size_t)(bn * 128 + srow) * HIDDEN + scol;
  unsigned short* Asw = &As[srow * PLD + scol];
  unsigned short* Bsw = &Bs[srow * PLD + scol];

  f32x4 acc[4][4];
#pragma unroll
  for (int i = 0; i < 4; i++)
#pragma unroll
    for (int j = 0; j < 4; j++) acc[i][j] = (f32x4){0.f, 0.f, 0.f, 0.f};

  for (int k0 = 0; k0 < HIDDEN; k0 += 64) {
    stage32(Ap + k0, Asw);
    stage32(Bp + k0, Bsw);
    __syncthreads();
#pragma unroll
    for (int kk = 0; kk < 64; kk += 32) {
      bf16x8 af[4], bfr[4];
#pragma unroll
      for (int i = 0; i < 4; i++)
        af[i] = ld_frag(&As[(wm * 64 + i * 16 + lr) * PLD + kk + lq * 8]);
#pragma unroll
      for (int j = 0; j < 4; j++)
        bfr[j] = ld_frag(&Bs[(wn * 64 + j * 16 + lr) * PLD + kk + lq * 8]);
#pragma unroll
      for (int i = 0; i < 4; i++)
#pragma unroll
        for (int j = 0; j < 4; j++)
          acc[i][j] = __builtin_amdgcn_mfma_f32_16x16x32_bf16(af[i], bfr[j], acc[i][j], 0, 0, 0);
    }
    __syncthreads();
  }

#pragma unroll
  for (int j = 0; j < 4; j++) {
    const int n = bn * 128 + wn * 64 + j * 16 + lr;
    const float bb = bias[n];
    const int h = n >> 6, d = n & 63;
#pragma unroll
    for (int i = 0; i < 4; i++) {
      const int mb = bm * 128 + wm * 64 + i * 16 + lq * 4;
#pragma unroll
      for (int r = 0; r < 4; r++) {
        const int m = mb + r;
        const int t = m >> 2, b = m & 3;
        float vv = acc[i][j][r] + bb;
        vv = fminf(fmaxf(vv, 0.0f), 6.0f);              // relu6
        if (VT) {
          const int s = t;
          const int st = s >> 7, sl = s & 127;
          const int a = (sl & 15) * 8 + (sl >> 4);
          out[(size_t)(b * NH + h) * HEADSZ + (size_t)d * TT + st * 128 + a] = f2bf(vv);
        } else {
          out[(size_t)(b * NH + h) * HEADSZ + (size_t)t * HD + d] = f2bf(vv);
        }
      }
    }
  }
}

// ---------------------------------------------------------------------------
// Flash attention, fixed-bias softmax (no online max):
//   P = exp2(S*csc - MBIAS), O = (P@V), l = (P@ones); out = O/l.
// R6 body restored EXACTLY (R7's V-direct + launch_bounds(256,4) spilled:
// VGPR 84->64, +510 MB scratch writes, 152->267 µs. Rule: this structure has
// zero VGPR headroom -- no new live state, no occupancy forcing).
// R8's only change: flat 1024-block grid + bijective XCD-chunk swizzle so the
// 16 qt-blocks sharing one (b,h) K/V plane (512 KB) run on ONE XCD (default
// mapping spreads them across all 8 -> 8x L2-fill duplication; FETCH_SIZE
// 141 MB vs ~75 MB ideal).
// LDS 52224 B -> 3 blocks/CU. 4 barriers/tile.
// ---------------------------------------------------------------------------
#define QLD 72
#define PLDS 136
#define VLD 136
#define MBIAS 24.0f

__global__ __launch_bounds__(256, 3)
void attn_kernel(const unsigned short* __restrict__ qh,
                 const unsigned short* __restrict__ kh,
                 const unsigned short* __restrict__ vh,
                 float* __restrict__ outp)
{
  __shared__ unsigned short KPs[128 * PLDS];   // 34816 B (K @72 / P @136)
  __shared__ unsigned short Vt[64 * VLD];      // 17408 B

  const int tid = threadIdx.x;
  const int lane = tid & 63;
  const int w = tid >> 6;
  const int lr = lane & 15, lq = lane >> 4;

  // ---- XCD-chunk swizzle over flat grid of 1024 (bijective: 1024%8==0) ----
  // XCD x gets swz in [x*128, x*128+128) = bh in [x*8, x*8+8), all 16 qt each:
  // the 16 blocks sharing a K/V plane are consecutive on one XCD -> L2-hot.
  const int id = blockIdx.x;
  const int swz = (id & 7) * 128 + (id >> 3);
  const int qt = swz & 15, bh = swz >> 4;
  const int b = bh >> 4, h = bh & 15;
  const int t0 = qt * 128;

  const size_t headoff = (size_t)bh * HEADSZ;

  // ---- load Q tile through LDS once, keep fragments in registers ----
  {
    const unsigned short* qb = qh + headoff + (size_t)t0 * HD;
    const int row = tid >> 1, c0 = (tid & 1) * 32;
    stage32(qb + (size_t)row * HD + c0, &KPs[row * QLD + c0]);
  }
  __syncthreads();
  bf16x8 aq[2][2];
#pragma unroll
  for (int i = 0; i < 2; i++)
#pragma unroll
    for (int kx = 0; kx < 2; kx++)
      aq[i][kx] = ld_frag(&KPs[(w * 32 + i * 16 + lr) * QLD + kx * 32 + lq * 8]);
  __syncthreads();

  // ones-column B-frag (B[n]=1 iff n==0) -- l accumulates as O column 0
  union { u16x8 v; unsigned short s[8]; } uo;
  const unsigned short ov = (lr == 0) ? (unsigned short)0x3F80 : (unsigned short)0;
#pragma unroll
  for (int z = 0; z < 8; z++) uo.s[z] = ov;
  const bf16x8 onesf = __builtin_bit_cast(bf16x8, uo.v);

  f32x4 Oacc[2][4];
  f32x4 lacc[2];
#pragma unroll
  for (int i = 0; i < 2; i++) {
#pragma unroll
    for (int jo = 0; jo < 4; jo++) Oacc[i][jo] = (f32x4){0.f, 0.f, 0.f, 0.f};
    lacc[i] = (f32x4){0.f, 0.f, 0.f, 0.f};
  }

  const float csc = 0.1803368801111204f;   // log2(e) / sqrt(64)

  for (int st = 0; st < TT / 128; st++) {
    // ---- stage K tile [s][d] @ stride QLD ----
    {
      const unsigned short* kb = kh + headoff + (size_t)st * (128 * HD);
      const int row = tid >> 1, c0 = (tid & 1) * 32;
      stage32(kb + (size_t)row * HD + c0, &KPs[row * QLD + c0]);
    }
    // ---- stage Vt tile [d][a] from pre-transposed vh (coalesced b128) ----
    {
      const unsigned short* vb = vh + headoff + st * 128;
      const int dd = tid >> 2, a0 = (tid & 3) * 32;
#pragma unroll
      for (int u = 0; u < 4; u++)
        *(u16x8*)&Vt[dd * VLD + a0 + u * 8] = *(const u16x8*)(vb + (size_t)dd * TT + a0 + u * 8);
    }
    __syncthreads();

    // ---- S = Q K^T ----
    f32x4 sc[2][8];
#pragma unroll
    for (int i = 0; i < 2; i++)
#pragma unroll
      for (int j = 0; j < 8; j++) sc[i][j] = (f32x4){0.f, 0.f, 0.f, 0.f};

    __builtin_amdgcn_s_setprio(1);
#pragma unroll
    for (int kx = 0; kx < 2; kx++) {
#pragma unroll
      for (int j = 0; j < 8; j++) {
        bf16x8 bk = ld_frag(&KPs[(j * 16 + lr) * QLD + kx * 32 + lq * 8]);
#pragma unroll
        for (int i = 0; i < 2; i++)
          sc[i][j] = __builtin_amdgcn_mfma_f32_16x16x32_bf16(aq[i][kx], bk, sc[i][j], 0, 0, 0);
      }
    }
    __builtin_amdgcn_s_setprio(0);
    __syncthreads();   // all K reads done before P overwrites the union buffer

    // ---- P = exp2(S*csc - MBIAS)  (no max pass, no rescale) ----
#pragma unroll
    for (int i = 0; i < 2; i++)
#pragma unroll
      for (int j = 0; j < 8; j++)
#pragma unroll
        for (int r = 0; r < 4; r++)
          sc[i][j][r] = exp2f(fmaf(sc[i][j][r], csc, -MBIAS));

    // ---- P -> LDS @ stride PLDS: lane's 8 cols contiguous at kpos=lr*8 ----
    // Psm[m][k=lr*8+j] = P[m][s_local = j*16+lr]  (matches Vt's sigma order)
#pragma unroll
    for (int i = 0; i < 2; i++)
#pragma unroll
      for (int r = 0; r < 4; r++) {
        const int row = w * 32 + i * 16 + lq * 4 + r;
        u32x4 pk;
        pk.x = packpair(sc[i][0][r], sc[i][1][r]);
        pk.y = packpair(sc[i][2][r], sc[i][3][r]);
        pk.z = packpair(sc[i][4][r], sc[i][5][r]);
        pk.w = packpair(sc[i][6][r], sc[i][7][r]);
        *(u16x8*)&KPs[row * PLDS + lr * 8] = __builtin_bit_cast(u16x8, pk);
      }
    __syncthreads();   // P visible before PV reads

    // ---- O += P V  (+ l via ones column) ----
    __builtin_amdgcn_s_setprio(1);
#pragma unroll
    for (int ks = 0; ks < 128; ks += 32) {
      bf16x8 ap[2];
#pragma unroll
      for (int i = 0; i < 2; i++)
        ap[i] = ld_frag(&KPs[(w * 32 + i * 16 + lr) * PLDS + ks + lq * 8]);
#pragma unroll
      for (int jo = 0; jo < 4; jo++) {
        bf16x8 bv2 = ld_frag(&Vt[(jo * 16 + lr) * VLD + ks + lq * 8]);
#pragma unroll
        for (int i = 0; i < 2; i++)
          Oacc[i][jo] = __builtin_amdgcn_mfma_f32_16x16x32_bf16(ap[i], bv2, Oacc[i][jo], 0, 0, 0);
      }
#pragma unroll
      for (int i = 0; i < 2; i++)
        lacc[i] = __builtin_amdgcn_mfma_f32_16x16x32_bf16(ap[i], onesf, lacc[i], 0, 0, 0);
    }
    __builtin_amdgcn_s_setprio(0);
    __syncthreads();   // P/Vt reads done before next iteration's staging
  }

  // ---- epilogue: l sits in col 0 (lanes lr==0); broadcast within 16-group ----
#pragma unroll
  for (int i = 0; i < 2; i++)
#pragma unroll
    for (int r = 0; r < 4; r++) {
      const float l = __shfl(lacc[i][r], lane & 48);
      const float inv = 1.0f / l;
      const int t = t0 + w * 32 + i * 16 + lq * 4 + r;
      float* op = outp + ((size_t)t * NB + b) * HIDDEN + h * HD;
#pragma unroll
      for (int jo = 0; jo < 4; jo++)
        op[jo * 16 + lr] = Oacc[i][jo][r] * inv;
    }
}

extern "C" void kernel_launch(void* const* d_in, const int* in_sizes, int n_in,
                              void* d_out, int out_size, void* d_ws, size_t ws_size,
                              hipStream_t stream)
{
  const float* q  = (const float*)d_in[0];
  const float* k  = (const float*)d_in[1];
  const float* v  = (const float*)d_in[2];
  const float* Wq = (const float*)d_in[3];
  const float* bq = (const float*)d_in[4];
  const float* Wk = (const float*)d_in[5];
  const float* bk = (const float*)d_in[6];
  const float* Wv = (const float*)d_in[7];
  const float* bv = (const float*)d_in[8];

  const size_t actN = (size_t)MROWS * HIDDEN;       // 8.4M elements
  const size_t WN   = (size_t)HIDDEN * HIDDEN;      // 1M elements
  unsigned short* qh  = (unsigned short*)d_ws;
  unsigned short* kh  = qh + actN;
  unsigned short* vh  = kh + actN;                  // vh: [b][h][d][perm-s]
  unsigned short* Wb3 = vh + actN;                  // 3x converted W (6.3 MB)
  unsigned short* Xb3 = Wb3 + 3 * WN;               // 3x converted X (50.3 MB)

  const size_t need_fused = (6 * actN + 3 * WN) * 2;     // 107.0 MB
  const size_t need_full  = (4 * actN + WN) * 2;         // 69.2 MB
  const size_t need_w     = (3 * actN + WN) * 2;         // 52.4 MB

  const int n4a = (int)(actN / 4);
  const int n4w = (int)(WN / 4);
  dim3 cga((n4a + 255) / 256), cgw((n4w + 255) / 256);
  dim3 pg(HIDDEN / 128, MROWS / 128);               // (8, 64)
  dim3 pf(HIDDEN / 128, MROWS / 128, 3);            // (8, 64, 3) fused
  dim3 ag(TT / 128 * NB * NH);                      // flat 1024, XCD-swizzled in-kernel

  if (ws_size >= need_fused) {
    dim3 cw(cgw.x, 3), cx(cga.x, 3);
    cvt3_kernel<<<cw, 256, 0, stream>>>(Wq, Wk, Wv, Wb3, n4w, (long long)(WN / 4));
    cvt3_kernel<<<cx, 256, 0, stream>>>(q, k, v, Xb3, n4a, (long long)(actN / 4));
    projc_kernel<<<pf, 256, 0, stream>>>(Xb3, Wb3, bq, bk, bv, qh, kh, vh);
  } else if (ws_size >= need_full) {
    unsigned short* Wbf = vh + actN;
    unsigned short* Xbf = Wbf + WN;
    cvt_kernel<<<cga, 256, 0, stream>>>(q, Xbf, n4a);
    cvt_kernel<<<cgw, 256, 0, stream>>>(Wq, Wbf, n4w);
    projg_kernel<0><<<pg, 256, 0, stream>>>(Xbf, Wbf, bq, qh);
    cvt_kernel<<<cga, 256, 0, stream>>>(k, Xbf, n4a);
    cvt_kernel<<<cgw, 256, 0, stream>>>(Wk, Wbf, n4w);
    projg_kernel<0><<<pg, 256, 0, stream>>>(Xbf, Wbf, bk, kh);
    cvt_kernel<<<cga, 256, 0, stream>>>(v, Xbf, n4a);
    cvt_kernel<<<cgw, 256, 0, stream>>>(Wv, Wbf, n4w);
    projg_kernel<1><<<pg, 256, 0, stream>>>(Xbf, Wbf, bv, vh);
  } else if (ws_size >= need_w) {
    unsigned short* Wbf = vh + actN;
    cvt_kernel<<<cgw, 256, 0, stream>>>(Wq, Wbf, n4w);
    proj_kernel<0, float, unsigned short><<<pg, 256, 0, stream>>>(q, Wbf, bq, qh);
    cvt_kernel<<<cgw, 256, 0, stream>>>(Wk, Wbf, n4w);
    proj_kernel<0, float, unsigned short><<<pg, 256, 0, stream>>>(k, Wbf, bk, kh);
    cvt_kernel<<<cgw, 256, 0, stream>>>(Wv, Wbf, n4w);
    proj_kernel<1, float, unsigned short><<<pg, 256, 0, stream>>>(v, Wbf, bv, vh);
  } else {
    proj_kernel<0, float, float><<<pg, 256, 0, stream>>>(q, Wq, bq, qh);
    proj_kernel<0, float, float><<<pg, 256, 0, stream>>>(k, Wk, bk, kh);
    proj_kernel<1, float, float><<<pg, 256, 0, stream>>>(v, Wv, bv, vh);
  }

  attn_kernel<<<ag, 256, 0, stream>>>(qh, kh, vh, (float*)d_out);
}